// Round 1
// baseline (416.600 us; speedup 1.0000x reference)
//
#include <hip/hip_runtime.h>
#include <hip/hip_bf16.h>
#include <cstdint>

#define D_MODEL 2048
#define D_REC   384
#define NPROJ   1152          // 3*D_REC
#define BATCH   4
#define SEQ     4096
#define M_TOTAL (BATCH*SEQ)   // 16384
#define CHUNK   64
#define NCHUNK  (SEQ/CHUNK)   // 64

// GEMM v2 geometry
#define BM 256
#define BN 96
#define BK 64
#define NTILE (D_MODEL/BK)    // 32 K-tiles

typedef __attribute__((ext_vector_type(8))) short  short8;
typedef __attribute__((ext_vector_type(4))) float  f32x4;

__device__ __forceinline__ float rcpf(float x) { return __builtin_amdgcn_rcpf(x); }

// ---------------------------------------------------------------- convert
__device__ __forceinline__ uint16_t f2bf(float x) {
    __hip_bfloat16 h = __float2bfloat16(x);
    return *reinterpret_cast<uint16_t*>(&h);
}

__global__ void cvt_bf16(const float* __restrict__ src, uint16_t* __restrict__ dst, long n) {
    long i = ((long)blockIdx.x * blockDim.x + threadIdx.x) * 4;
    if (i + 3 >= n) return;
    float4 f = *reinterpret_cast<const float4*>(src + i);
    ushort4 o;
    o.x = f2bf(f.x); o.y = f2bf(f.y); o.z = f2bf(f.z); o.w = f2bf(f.w);
    *reinterpret_cast<ushort4*>(dst + i) = o;
}

// ---------------------------------------------------------------- GEMM v2
// C[m][n] = sum_k A[m][k]*B[n][k].  BM=256 x BN=96 tile, BK=64, 8 waves (4M x 2N),
// per-wave 64x48.  Grid 64x12 = 768 blocks = exactly 3 blocks/CU (no round tail).
// Triple-buffered LDS (prefetch distance 2) + counted vmcnt: the end-of-tile wait
// is vmcnt(6)/vmcnt(5) with the t+2 tile's loads still in flight (T3+T4); setprio
// around each MFMA cluster (T5); per-phase raw s_barrier lockstep.
// XOR-swizzled LDS: LDS[r][c8] = G[r][c8 ^ (r&7)] (16B chunks), applied on the
// GLOBAL source address so global_load_lds dest stays base + lane*16 (linear).
__device__ __forceinline__ void gload_lds16(const uint16_t* g, uint16_t* l) {
    __builtin_amdgcn_global_load_lds(
        (__attribute__((address_space(1))) void*)g,
        (__attribute__((address_space(3))) void*)l,
        16, 0, 0);
}

__launch_bounds__(512, 1)
__global__ void gemm_bf16nt_v2(const uint16_t* __restrict__ A,   // [16384][2048]
                               const uint16_t* __restrict__ Bm,  // [1152][2048]
                               float* __restrict__ C)            // [16384][1152]
{
    __shared__ __align__(16) uint16_t As[3 * BM * BK];  // 96 KiB
    __shared__ __align__(16) uint16_t Bs[3 * BN * BK];  // 36 KiB

    const int tid  = threadIdx.x;
    const int wave = tid >> 6;
    const int lane = tid & 63;

    // bijective XCD-chunked tile swizzle (768 % 8 == 0): each XCD gets 96
    // consecutive jobs = 1.5 B-panels -> B stays L2-resident per XCD.
    const int flat = blockIdx.y * 64 + blockIdx.x;       // 0..767
    const int job  = (flat & 7) * 96 + (flat >> 3);
    const int m0 = (job & 63) * BM;                      // 64 m-tiles
    const int n0 = (job >> 6) * BN;                      // 12 n-tiles

    const int wm = (wave >> 1) * 64;                     // 4 M-waves
    const int wn = (wave & 1) * 48;                      // 2 N-waves

    // ---- staging addressing (8 rows per wave per call; swizzled global src)
    const int rq = tid >> 3;                  // 0..63: row within a 64-row call
    const int cg = (tid & 7) ^ (rq & 7);      // swizzled 16B chunk
    const long aSrc0 = (long)(m0 + rq) * D_MODEL + cg * 8;
    const long bSrc0 = (long)(n0 + rq) * D_MODEL + cg * 8;
    uint16_t* AsW = &As[(wave * 8) * BK];
    uint16_t* BsW = &Bs[(wave * 8) * BK];

    // ---- fragment addressing
    const int lm = lane & 15;
    const int qq = lane >> 4;
    const int h  = lm & 7;
    const uint16_t* AsR = &As[(wm + lm) * BK];
    const uint16_t* BsR = &Bs[(wn + lm) * BK];

    f32x4 acc[4][3];
#pragma unroll
    for (int i = 0; i < 4; ++i)
#pragma unroll
        for (int jn = 0; jn < 3; ++jn) acc[i][jn] = (f32x4){0.f, 0.f, 0.f, 0.f};

    // ---- prologue: stage K-tiles 0 and 1 into bufs 0,1
#pragma unroll
    for (int t = 0; t < 2; ++t) {
        const long ak = aSrc0 + t * BK;
        const long bk = bSrc0 + t * BK;
#pragma unroll
        for (int jj = 0; jj < 4; ++jj)
            gload_lds16(A + ak + (long)(64 * jj) * D_MODEL,
                        AsW + t * (BM * BK) + (64 * jj) * BK);
        gload_lds16(Bm + bk, BsW + t * (BN * BK));
        if (wave < 4)
            gload_lds16(Bm + bk + (long)64 * D_MODEL, BsW + t * (BN * BK) + 64 * BK);
    }
    // wait tile0 landed; tile1 (6/5 own calls) stays in flight
    if (wave < 4) asm volatile("s_waitcnt vmcnt(6)" ::: "memory");
    else          asm volatile("s_waitcnt vmcnt(5)" ::: "memory");
    __builtin_amdgcn_sched_barrier(0);
    __builtin_amdgcn_s_barrier();

    int cur = 0;
    for (int t = 0; t < NTILE; ++t) {
        int nxt = cur + 2; if (nxt >= 3) nxt -= 3;
        const bool pf = (t + 2) < NTILE;
        const long ak = aSrc0 + (long)(t + 2) * BK;
        const long bk = bSrc0 + (long)(t + 2) * BK;
        const uint16_t* AsC = AsR + cur * (BM * BK);
        const uint16_t* BsC = BsR + cur * (BN * BK);
        uint16_t* AsN = AsW + nxt * (BM * BK);
        uint16_t* BsN = BsW + nxt * (BN * BK);

        // A fragments for the whole tile, read once (8x ds_read_b128)
        short8 af[4][2];
#pragma unroll
        for (int mt = 0; mt < 4; ++mt)
#pragma unroll
            for (int s = 0; s < 2; ++s)
                af[mt][s] = *reinterpret_cast<const short8*>(
                    &AsC[mt * 16 * BK + (((s * 4 + qq) ^ h) * 8)]);

#pragma unroll
        for (int p = 0; p < 3; ++p) {
            // stage part of tile t+2 (2 calls/phase for waves<4; A-phases for all)
            if (pf) {
                if (p < 2) {
                    gload_lds16(A + ak + (long)(64 * (2 * p)) * D_MODEL,
                                AsN + (64 * (2 * p)) * BK);
                    gload_lds16(A + ak + (long)(64 * (2 * p + 1)) * D_MODEL,
                                AsN + (64 * (2 * p + 1)) * BK);
                } else {
                    gload_lds16(Bm + bk, BsN);
                    if (wave < 4)
                        gload_lds16(Bm + bk + (long)64 * D_MODEL, BsN + 64 * BK);
                }
            }
            // B fragments for this n-phase
            short8 b0 = *reinterpret_cast<const short8*>(
                &BsC[p * 16 * BK + (((0 + qq) ^ h) * 8)]);
            short8 b1 = *reinterpret_cast<const short8*>(
                &BsC[p * 16 * BK + (((4 + qq) ^ h) * 8)]);

            __builtin_amdgcn_s_barrier();
            __builtin_amdgcn_s_setprio(1);
#pragma unroll
            for (int mt = 0; mt < 4; ++mt) {
                acc[mt][p] = __builtin_amdgcn_mfma_f32_16x16x32_bf16(af[mt][0], b0, acc[mt][p], 0, 0, 0);
                acc[mt][p] = __builtin_amdgcn_mfma_f32_16x16x32_bf16(af[mt][1], b1, acc[mt][p], 0, 0, 0);
            }
            __builtin_amdgcn_s_setprio(0);
            __builtin_amdgcn_s_barrier();
        }

        // end of tile: ensure tile t+1 landed; keep tile t+2 (6/5 calls) in flight
        if (t + 1 < NTILE) {
            if (pf) {
                if (wave < 4) asm volatile("s_waitcnt vmcnt(6)" ::: "memory");
                else          asm volatile("s_waitcnt vmcnt(5)" ::: "memory");
            } else {
                asm volatile("s_waitcnt vmcnt(0)" ::: "memory");
            }
            __builtin_amdgcn_sched_barrier(0);
            __builtin_amdgcn_s_barrier();
        }
        cur = cur + 1 == 3 ? 0 : cur + 1;
    }

    // ---- epilogue: D[m = qq*4 + r][n = lm]
#pragma unroll
    for (int mt = 0; mt < 4; ++mt) {
#pragma unroll
        for (int nt = 0; nt < 3; ++nt) {
            const int row = m0 + wm + mt * 16 + qq * 4;
            const int col = n0 + wn + nt * 16 + lm;
#pragma unroll
            for (int r = 0; r < 4; ++r)
                C[(long)(row + r) * NPROJ + col] = acc[mt][nt][r];
        }
    }
}

// ---------------------------------------------------------------- intra-chunk scan
// grid (NCHUNK, BATCH, 3), block 128. Running clipped product == exp(cumsum(log(clip)))
// (identical incl. underflow->0). Stores cumdec & cumw; final kernel combines.
__global__ void intra_scan(const float* __restrict__ aiv, const float* __restrict__ bias,
                           float* __restrict__ cumw_out,  // [B][S][D]
                           float* __restrict__ cumdec,    // [B][S][D]
                           float* __restrict__ ctd,       // [B][NCHUNK][D]
                           float* __restrict__ cfs)       // [B][NCHUNK][D]
{
    const int d = blockIdx.z * 128 + threadIdx.x;
    const int c = blockIdx.x;
    const int b = blockIdx.y;
    const float bias_d = bias[d];

    const long rowbase = ((long)b * SEQ + (long)c * CHUNK) * NPROJ;
    const long obase   = ((long)b * SEQ + (long)c * CHUNK) * D_REC;

    float cd = 1.f, cw = 0.f;

    // prefetch t=0
    float ap = aiv[rowbase + d];
    float ip = aiv[rowbase + D_REC + d];
    float vv = aiv[rowbase + 2 * D_REC + d];

    for (int t = 0; t < CHUNK; ++t) {
        float ap_n, ip_n, vv_n;
        if (t + 1 < CHUNK) {
            const long rn = rowbase + (long)(t + 1) * NPROJ;
            ap_n = aiv[rn + d];
            ip_n = aiv[rn + D_REC + d];
            vv_n = aiv[rn + 2 * D_REC + d];
        }
        const float a = rcpf(1.f + __expf(-(ap + bias_d)));
        const float g = rcpf(1.f + __expf(-ip));
        const float sig = sqrtf(fmaxf(1.f - a * a, 1e-8f)) * (g * vv);

        cd *= fmaxf(a, 1e-10f);
        cw += sig * rcpf(fmaxf(cd, 1e-10f));

        cumdec[obase + (long)t * D_REC + d]   = cd;
        cumw_out[obase + (long)t * D_REC + d] = cw;

        ap = ap_n; ip = ip_n; vv = vv_n;
    }
    const long cb = ((long)b * NCHUNK + c) * D_REC + d;
    ctd[cb] = cd;
    cfs[cb] = cd * cw;
}

// ---------------------------------------------------------------- cross-chunk scan
__global__ void cross_scan(const float* __restrict__ ctd, const float* __restrict__ cfs,
                           float* __restrict__ incoming)  // [B][NCHUNK][D]
{
    const int d = threadIdx.x;
    const int b = blockIdx.x;
    float cdk = 1.f, cwk = 0.f;
    incoming[(long)b * NCHUNK * D_REC + d] = 0.f;
#pragma unroll 4
    for (int c = 0; c < NCHUNK; ++c) {
        const long idx = ((long)b * NCHUNK + c) * D_REC + d;
        const float td = ctd[idx];
        const float fs = cfs[idx];
        cdk *= fmaxf(td, 1e-10f);
        cwk += fs * rcpf(fmaxf(cdk, 1e-10f));
        if (c + 1 < NCHUNK) incoming[idx + D_REC] = cdk * cwk;
    }
}

// ---------------------------------------------------------------- final combine
// out = cumdec * (cumw + incoming[b][s/64][d]), vectorized float4
__global__ void final_combine(const float* __restrict__ cumdec, const float* __restrict__ cumw,
                              const float* __restrict__ inc, float* __restrict__ out)
{
    const long i = ((long)blockIdx.x * blockDim.x + threadIdx.x) * 4;
    const float4 cd = *reinterpret_cast<const float4*>(cumdec + i);
    const float4 cw = *reinterpret_cast<const float4*>(cumw + i);
    const long chunk = i / ((long)D_REC * CHUNK);   // = b*64 + s/64
    const int  dd    = (int)(i % D_REC);
    const float4 ic = *reinterpret_cast<const float4*>(inc + chunk * D_REC + dd);
    float4 o;
    o.x = cd.x * (cw.x + ic.x);
    o.y = cd.y * (cw.y + ic.y);
    o.z = cd.z * (cw.z + ic.z);
    o.w = cd.w * (cw.w + ic.w);
    *reinterpret_cast<float4*>(out + i) = o;
}

// ---------------------------------------------------------------- launch
extern "C" void kernel_launch(void* const* d_in, const int* in_sizes, int n_in,
                              void* d_out, int out_size, void* d_ws, size_t ws_size,
                              hipStream_t stream) {
    const float* x  = (const float*)d_in[0];   // [4][4096][2048]
    const float* W  = (const float*)d_in[1];   // [1152][2048]
    const float* db = (const float*)d_in[2];   // [384]
    float* out = (float*)d_out;                // [4][4096][384]

    char* ws = (char*)d_ws;
    // layout (bytes): aiv 75.5MB | xb 64MB (dead after GEMM; cumdec+cumw overlay) | Wb 4.5MB
    float*    aiv    = (float*)   (ws + 0);                 // 75,497,472 B
    uint16_t* xb     = (uint16_t*)(ws + 75497472L);         // 67,108,864 B
    uint16_t* Wb     = (uint16_t*)(ws + 142606336L);        //  4,718,592 B
    float*    cumdec = (float*)   (ws + 75497472L);         // 25,165,824 B (overlays xb)
    float*    cumw   = (float*)   (ws + 100663296L);        // 25,165,824 B (overlays xb)
    float*    ctd    = (float*)   (ws + 125829120L);        //    393,216 B
    float*    cfs    = (float*)   (ws + 126222336L);        //    393,216 B
    float*    inc    = (float*)   (ws + 126615552L);        //    393,216 B

    // 1. convert x, W to bf16
    {
        const long nx = (long)M_TOTAL * D_MODEL;
        cvt_bf16<<<(int)(nx / (4 * 256)), 256, 0, stream>>>(x, xb, nx);
        const long nw = (long)NPROJ * D_MODEL;
        cvt_bf16<<<(int)(nw / (4 * 256)), 256, 0, stream>>>(W, Wb, nw);
    }

    // 2. aiv = x . W^T via bf16 MFMA (BM=256 x BN=96, 8 waves, triple-buffered)
    gemm_bf16nt_v2<<<dim3(M_TOTAL / BM, NPROJ / BN), 512, 0, stream>>>(xb, Wb, aiv);

    // 3. intra-chunk scan (gates + running product), writes cumdec/cumw
    intra_scan<<<dim3(NCHUNK, BATCH, 3), 128, 0, stream>>>(aiv, db, cumw, cumdec, ctd, cfs);

    // 4. cross-chunk scan
    cross_scan<<<BATCH, D_REC, 0, stream>>>(ctd, cfs, inc);

    // 5. combine: out = cumdec * (cumw + incoming)
    final_combine<<<(int)((long)M_TOTAL * D_REC / (4 * 256)), 256, 0, stream>>>(cumdec, cumw, inc, out);
}

// Round 2
// 324.162 us; speedup vs baseline: 1.2852x; 1.2852x over previous
//
#include <hip/hip_runtime.h>
#include <hip/hip_bf16.h>
#include <cstdint>

#define D_MODEL 2048
#define D_REC   384
#define NPROJ   1152          // 3*D_REC
#define BATCH   4
#define SEQ     4096
#define M_TOTAL (BATCH*SEQ)   // 16384
#define CHUNK   64
#define NCHUNK  (SEQ/CHUNK)   // 64

// GEMM v3 geometry: BM x BN chosen so grid = 64 x 4 = 256 blocks = 1/CU exactly.
#define BM 256
#define BN 288
#define BK 64
#define NTILE (D_MODEL/BK)    // 32 K-tiles

typedef __attribute__((ext_vector_type(8))) short  short8;
typedef __attribute__((ext_vector_type(4))) float  f32x4;

__device__ __forceinline__ float rcpf(float x) { return __builtin_amdgcn_rcpf(x); }

// ---------------------------------------------------------------- convert
__device__ __forceinline__ uint16_t f2bf(float x) {
    __hip_bfloat16 h = __float2bfloat16(x);
    return *reinterpret_cast<uint16_t*>(&h);
}

__global__ void cvt_bf16(const float* __restrict__ src, uint16_t* __restrict__ dst, long n) {
    long i = ((long)blockIdx.x * blockDim.x + threadIdx.x) * 4;
    if (i + 3 >= n) return;
    float4 f = *reinterpret_cast<const float4*>(src + i);
    ushort4 o;
    o.x = f2bf(f.x); o.y = f2bf(f.y); o.z = f2bf(f.z); o.w = f2bf(f.w);
    *reinterpret_cast<ushort4*>(dst + i) = o;
}

// ---------------------------------------------------------------- GEMM v3
// C[m][n] = sum_k A[m][k]*B[n][k].  256x288 tile, BK=64, 8 waves (4M x 2N),
// per-wave 64x144 (acc 4x9 f32x4).  Grid 64x4 = 256 blocks = exactly 1/CU,
// single round.  Double-buffered LDS (139 KB), ONE barrier + vmcnt drain per
// K-tile amortized over 72 MFMAs/wave; stage issues pinned at iteration top so
// the drain lands after ~700 cycles of ds_read+MFMA cover.  Natural dispatch
// order (no swizzle) - v1-proven L3 locality.  XOR-swizzled LDS staging
// identical to the verified v1 scheme (0 bank conflicts measured).
__device__ __forceinline__ void gload_lds16(const uint16_t* g, uint16_t* l) {
    __builtin_amdgcn_global_load_lds(
        (__attribute__((address_space(1))) void*)g,
        (__attribute__((address_space(3))) void*)l,
        16, 0, 0);
}

__launch_bounds__(512, 2)
__global__ void gemm_bf16nt_v3(const uint16_t* __restrict__ A,   // [16384][2048]
                               const uint16_t* __restrict__ Bm,  // [1152][2048]
                               float* __restrict__ C)            // [16384][1152]
{
    __shared__ __align__(16) uint16_t As[2][BM * BK];  // 2 x 32 KiB
    __shared__ __align__(16) uint16_t Bs[2][BN * BK];  // 2 x 36 KiB

    const int tid  = threadIdx.x;
    const int wave = tid >> 6;
    const int lane = tid & 63;
    const int m0 = blockIdx.x * BM;
    const int n0 = blockIdx.y * BN;
    const int wm = (wave >> 1) * 64;     // 4 M-waves
    const int wn = (wave & 1) * 144;     // 2 N-waves

    // ---- staging addressing (8 rows x 8 chunks per wave-call, swizzled src)
    const int rl = lane >> 3;            // 0..7 row within call
    const int cg = (lane & 7) ^ rl;      // swizzled 16B chunk
    // A: wave w stages rows [w*32, w*32+32) in 4 calls of 8 rows.
    // B: waves 0-3 stage 5 calls (rows 0..159), waves 4-7 stage 4 (160..287).
    const int ncb = (wave < 4) ? 5 : 4;
    const int cb0 = (wave < 4) ? wave * 5 : 20 + (wave - 4) * 4;
    const long aStage = (long)(m0 + wave * 32 + rl) * D_MODEL + cg * 8;
    const long bStage = (long)(n0 + cb0 * 8  + rl) * D_MODEL + cg * 8;

    // ---- fragment addressing
    const int lm = lane & 15;
    const int qq = lane >> 4;
    const int h  = lm & 7;

    f32x4 acc[4][9];
#pragma unroll
    for (int i = 0; i < 4; ++i)
#pragma unroll
        for (int j = 0; j < 9; ++j) acc[i][j] = (f32x4){0.f, 0.f, 0.f, 0.f};

    // ---- prologue: stage K-tile 0 into buf 0
    {
#pragma unroll
        for (int j = 0; j < 4; ++j)
            gload_lds16(A + aStage + (long)(8 * j) * D_MODEL,
                        &As[0][(wave * 32 + 8 * j) * 64]);
#pragma unroll
        for (int j = 0; j < 5; ++j)
            if (j < ncb)
                gload_lds16(Bm + bStage + (long)(8 * j) * D_MODEL,
                            &Bs[0][((cb0 + j) * 8) * 64]);
    }
    asm volatile("s_waitcnt vmcnt(0)" ::: "memory");
    __builtin_amdgcn_sched_barrier(0);
    __builtin_amdgcn_s_barrier();

    int buf = 0;
    for (int t = 0; t < NTILE; ++t) {
        // stage tile t+1 into the other buffer, issued FIRST for max latency cover
        if (t + 1 < NTILE) {
            const long k0 = (long)(t + 1) * BK;
            uint16_t* asb = &As[buf ^ 1][0];
            uint16_t* bsb = &Bs[buf ^ 1][0];
#pragma unroll
            for (int j = 0; j < 4; ++j)
                gload_lds16(A + aStage + k0 + (long)(8 * j) * D_MODEL,
                            asb + (wave * 32 + 8 * j) * 64);
#pragma unroll
            for (int j = 0; j < 5; ++j)
                if (j < ncb)
                    gload_lds16(Bm + bStage + k0 + (long)(8 * j) * D_MODEL,
                                bsb + ((cb0 + j) * 8) * 64);
            __builtin_amdgcn_sched_barrier(0);   // keep stages ahead of compute
        }

        const uint16_t* ap = &As[buf][0];
        const uint16_t* bp = &Bs[buf][0];
#pragma unroll
        for (int s = 0; s < 2; ++s) {
            short8 af[4], bfr[9];
#pragma unroll
            for (int mt = 0; mt < 4; ++mt)
                af[mt] = *reinterpret_cast<const short8*>(
                    &ap[(wm + mt * 16 + lm) * 64 + (((s * 4 + qq) ^ h) * 8)]);
#pragma unroll
            for (int nt = 0; nt < 9; ++nt)
                bfr[nt] = *reinterpret_cast<const short8*>(
                    &bp[(wn + nt * 16 + lm) * 64 + (((s * 4 + qq) ^ h) * 8)]);
            __builtin_amdgcn_s_setprio(1);
#pragma unroll
            for (int mt = 0; mt < 4; ++mt)
#pragma unroll
                for (int nt = 0; nt < 9; ++nt)
                    acc[mt][nt] = __builtin_amdgcn_mfma_f32_16x16x32_bf16(
                        af[mt], bfr[nt], acc[mt][nt], 0, 0, 0);
            __builtin_amdgcn_s_setprio(0);
        }

        if (t + 1 < NTILE) {
            // drain own t+1 stages (issued ~700 cyc ago), then block-wide join
            asm volatile("s_waitcnt vmcnt(0)" ::: "memory");
            __builtin_amdgcn_sched_barrier(0);
            __builtin_amdgcn_s_barrier();
            buf ^= 1;
        }
    }

    // ---- epilogue: D[m = qq*4 + r][n = lm]
#pragma unroll
    for (int mt = 0; mt < 4; ++mt) {
#pragma unroll
        for (int nt = 0; nt < 9; ++nt) {
            const int row = m0 + wm + mt * 16 + qq * 4;
            const int col = n0 + wn + nt * 16 + lm;
#pragma unroll
            for (int r = 0; r < 4; ++r)
                C[(long)(row + r) * NPROJ + col] = acc[mt][nt][r];
        }
    }
}

// ---------------------------------------------------------------- intra-chunk scan
// grid (NCHUNK, BATCH, 3), block 128. Running clipped product == exp(cumsum(log(clip)))
// (identical incl. underflow->0). Stores cumdec & cumw; final kernel combines.
__global__ void intra_scan(const float* __restrict__ aiv, const float* __restrict__ bias,
                           float* __restrict__ cumw_out,  // [B][S][D]
                           float* __restrict__ cumdec,    // [B][S][D]
                           float* __restrict__ ctd,       // [B][NCHUNK][D]
                           float* __restrict__ cfs)       // [B][NCHUNK][D]
{
    const int d = blockIdx.z * 128 + threadIdx.x;
    const int c = blockIdx.x;
    const int b = blockIdx.y;
    const float bias_d = bias[d];

    const long rowbase = ((long)b * SEQ + (long)c * CHUNK) * NPROJ;
    const long obase   = ((long)b * SEQ + (long)c * CHUNK) * D_REC;

    float cd = 1.f, cw = 0.f;

    // prefetch t=0
    float ap = aiv[rowbase + d];
    float ip = aiv[rowbase + D_REC + d];
    float vv = aiv[rowbase + 2 * D_REC + d];

    for (int t = 0; t < CHUNK; ++t) {
        float ap_n, ip_n, vv_n;
        if (t + 1 < CHUNK) {
            const long rn = rowbase + (long)(t + 1) * NPROJ;
            ap_n = aiv[rn + d];
            ip_n = aiv[rn + D_REC + d];
            vv_n = aiv[rn + 2 * D_REC + d];
        }
        const float a = rcpf(1.f + __expf(-(ap + bias_d)));
        const float g = rcpf(1.f + __expf(-ip));
        const float sig = sqrtf(fmaxf(1.f - a * a, 1e-8f)) * (g * vv);

        cd *= fmaxf(a, 1e-10f);
        cw += sig * rcpf(fmaxf(cd, 1e-10f));

        cumdec[obase + (long)t * D_REC + d]   = cd;
        cumw_out[obase + (long)t * D_REC + d] = cw;

        ap = ap_n; ip = ip_n; vv = vv_n;
    }
    const long cb = ((long)b * NCHUNK + c) * D_REC + d;
    ctd[cb] = cd;
    cfs[cb] = cd * cw;
}

// ---------------------------------------------------------------- cross-chunk scan
__global__ void cross_scan(const float* __restrict__ ctd, const float* __restrict__ cfs,
                           float* __restrict__ incoming)  // [B][NCHUNK][D]
{
    const int d = threadIdx.x;
    const int b = blockIdx.x;
    float cdk = 1.f, cwk = 0.f;
    incoming[(long)b * NCHUNK * D_REC + d] = 0.f;
#pragma unroll 4
    for (int c = 0; c < NCHUNK; ++c) {
        const long idx = ((long)b * NCHUNK + c) * D_REC + d;
        const float td = ctd[idx];
        const float fs = cfs[idx];
        cdk *= fmaxf(td, 1e-10f);
        cwk += fs * rcpf(fmaxf(cdk, 1e-10f));
        if (c + 1 < NCHUNK) incoming[idx + D_REC] = cdk * cwk;
    }
}

// ---------------------------------------------------------------- final combine
// out = cumdec * (cumw + incoming[b][s/64][d]), vectorized float4
__global__ void final_combine(const float* __restrict__ cumdec, const float* __restrict__ cumw,
                              const float* __restrict__ inc, float* __restrict__ out)
{
    const long i = ((long)blockIdx.x * blockDim.x + threadIdx.x) * 4;
    const float4 cd = *reinterpret_cast<const float4*>(cumdec + i);
    const float4 cw = *reinterpret_cast<const float4*>(cumw + i);
    const long chunk = i / ((long)D_REC * CHUNK);   // = b*64 + s/64
    const int  dd    = (int)(i % D_REC);
    const float4 ic = *reinterpret_cast<const float4*>(inc + chunk * D_REC + dd);
    float4 o;
    o.x = cd.x * (cw.x + ic.x);
    o.y = cd.y * (cw.y + ic.y);
    o.z = cd.z * (cw.z + ic.z);
    o.w = cd.w * (cw.w + ic.w);
    *reinterpret_cast<float4*>(out + i) = o;
}

// ---------------------------------------------------------------- launch
extern "C" void kernel_launch(void* const* d_in, const int* in_sizes, int n_in,
                              void* d_out, int out_size, void* d_ws, size_t ws_size,
                              hipStream_t stream) {
    const float* x  = (const float*)d_in[0];   // [4][4096][2048]
    const float* W  = (const float*)d_in[1];   // [1152][2048]
    const float* db = (const float*)d_in[2];   // [384]
    float* out = (float*)d_out;                // [4][4096][384]

    char* ws = (char*)d_ws;
    // layout (bytes): aiv 75.5MB | xb 64MB (dead after GEMM; cumdec+cumw overlay) | Wb 4.5MB
    float*    aiv    = (float*)   (ws + 0);                 // 75,497,472 B
    uint16_t* xb     = (uint16_t*)(ws + 75497472L);         // 67,108,864 B
    uint16_t* Wb     = (uint16_t*)(ws + 142606336L);        //  4,718,592 B
    float*    cumdec = (float*)   (ws + 75497472L);         // 25,165,824 B (overlays xb)
    float*    cumw   = (float*)   (ws + 100663296L);        // 25,165,824 B (overlays xb)
    float*    ctd    = (float*)   (ws + 125829120L);        //    393,216 B
    float*    cfs    = (float*)   (ws + 126222336L);        //    393,216 B
    float*    inc    = (float*)   (ws + 126615552L);        //    393,216 B

    // 1. convert x, W to bf16
    {
        const long nx = (long)M_TOTAL * D_MODEL;
        cvt_bf16<<<(int)(nx / (4 * 256)), 256, 0, stream>>>(x, xb, nx);
        const long nw = (long)NPROJ * D_MODEL;
        cvt_bf16<<<(int)(nw / (4 * 256)), 256, 0, stream>>>(W, Wb, nw);
    }

    // 2. aiv = x . W^T via bf16 MFMA (256x288 tile, 8 waves, 1 block/CU, 1 round)
    gemm_bf16nt_v3<<<dim3(M_TOTAL / BM, NPROJ / BN), 512, 0, stream>>>(xb, Wb, aiv);

    // 3. intra-chunk scan (gates + running product), writes cumdec/cumw
    intra_scan<<<dim3(NCHUNK, BATCH, 3), 128, 0, stream>>>(aiv, db, cumw, cumdec, ctd, cfs);

    // 4. cross-chunk scan
    cross_scan<<<BATCH, D_REC, 0, stream>>>(ctd, cfs, inc);

    // 5. combine: out = cumdec * (cumw + incoming)
    final_combine<<<(int)((long)M_TOTAL * D_REC / (4 * 256)), 256, 0, stream>>>(cumdec, cumw, inc, out);
}